// Round 6
// baseline (53.367 us; speedup 1.0000x reference)
//
#include <hip/hip_runtime.h>
#include <math.h>

#define BB 4
#define TQ 256
#define TV 256
#define DD 512
#define UU 128
#define NEGV (-1e9f)

__device__ __forceinline__ float fast_rcp(float x) {
    return __builtin_amdgcn_rcpf(x);   // v_rcp_f32
}

// ---------------- kernel 1: projections -> Eq=exp(2q), Ek=exp(2k) (transposed) ----------------
// 512 blocks x 512 thr. blocks 0..255: q-proj, 256..511: k-proj. 4 rows/block.
// threads = 128 u-cols x 4 K-quarters, combined via LDS. 4 waves/SIMD.
__global__ __launch_bounds__(512, 4) void proj_kernel(
    const float* __restrict__ query, const float* __restrict__ value,
    const float* __restrict__ W1, const float* __restrict__ W2,
    float* __restrict__ eqp /* [B*TQ][U] = exp(2q) */,
    float* __restrict__ ekT /* [B][U][TV] = exp(2k) */) {
    int bid = blockIdx.x;
    int which = bid >> 8;              // 0 = q, 1 = k
    int row0 = (bid & 255) * 4;
    const float* X = which ? value : query;
    const float* W = which ? W2 : W1;

    __shared__ float xs[4 * DD];       // 8 KB: 4 input rows
    __shared__ float cmb[3][4][UU];    // 6 KB: split-K partials
    int tid = threadIdx.x;
    ((float4*)xs)[tid] = ((const float4*)(X + (size_t)row0 * DD))[tid];
    __syncthreads();

    int kc = tid >> 7;                 // K-quarter 0..3
    int u = tid & 127;
    const float* Wp = W + (size_t)(kc * (DD / 4)) * UU + u;
    const float* x0 = xs + kc * (DD / 4);
    float a0 = 0.f, a1 = 0.f, a2 = 0.f, a3 = 0.f;
    #pragma unroll 8
    for (int d = 0; d < DD / 4; ++d) {
        float w = Wp[(size_t)d * UU];          // coalesced across u
        a0 = fmaf(x0[d], w, a0);               // LDS broadcast
        a1 = fmaf(x0[DD + d], w, a1);
        a2 = fmaf(x0[2 * DD + d], w, a2);
        a3 = fmaf(x0[3 * DD + d], w, a3);
    }
    if (kc) {
        cmb[kc - 1][0][u] = a0; cmb[kc - 1][1][u] = a1;
        cmb[kc - 1][2][u] = a2; cmb[kc - 1][3][u] = a3;
    }
    __syncthreads();
    if (!kc) {
        a0 = __expf(2.f * (((a0 + cmb[0][0][u]) + cmb[1][0][u]) + cmb[2][0][u]));
        a1 = __expf(2.f * (((a1 + cmb[0][1][u]) + cmb[1][1][u]) + cmb[2][1][u]));
        a2 = __expf(2.f * (((a2 + cmb[0][2][u]) + cmb[1][2][u]) + cmb[2][2][u]));
        a3 = __expf(2.f * (((a3 + cmb[0][3][u]) + cmb[1][3][u]) + cmb[2][3][u]));
        if (which == 0) {
            float* p = eqp + (size_t)row0 * UU + u;
            p[0 * UU] = a0; p[1 * UU] = a1; p[2 * UU] = a2; p[3 * UU] = a3;
        } else {
            int b = row0 >> 8, v0 = row0 & 255;
            float* p = ekT + ((size_t)b * UU + u) * TV + v0;
            p[0] = a0; p[1] = a1; p[2] = a2; p[3] = a3;
        }
    }
}

// ---------------- kernel 2: scores + masked softmax -> weights ----------------
// 1024 blocks x 512 thr; block = 1 q-row; thread = (v, u-half). 8 waves/SIMD.
// s'[v] = -2 * sum_u sc_u * rcp(1 + Eq[u]*Ek[u,v])   (shift-invariant vs ref)
__global__ __launch_bounds__(512, 8) void scores_kernel(
    const float* __restrict__ eqp, const float* __restrict__ ekT,
    const float* __restrict__ scale, const unsigned char* __restrict__ m,
    float* __restrict__ weights) {
    int blk = blockIdx.x;              // 0..1023 = (b, q)
    int b = blk >> 8;
    int tid = threadIdx.x;
    int v = tid & 255;
    int h = tid >> 8;                  // u-half

    __shared__ float eqf[UU], sc2[UU];
    __shared__ float pb[TV];           // partial from h=1
    __shared__ int flagF, flagB;
    __shared__ float redM[4], redS[4];

    if (tid == 0) { flagF = 0; flagB = 0; }
    if (tid < UU) eqf[tid] = eqp[(size_t)blk * UU + tid];
    else if (tid < 2 * UU) sc2[tid - UU] = -2.f * scale[tid - UU];
    if (tid < 256) {                   // mask layout probe, first 1024 bytes safe
        uchar4 c4 = ((const uchar4*)m)[tid];
        if (c4.w == 0x3f) flagF = 1;                 // float32 1.0f high byte
        if (c4.y | c4.z | c4.w) flagB = 1;           // off-word nonzero -> u8
    }
    __syncthreads();

    const float* kb = ekT + ((size_t)b * UU + h * 64) * TV + v;
    const float* eqh = eqf + h * 64;
    const float* sch = sc2 + h * 64;
    float sA = 0.f, sB = 0.f;          // dual accumulators for ILP
    #pragma unroll 8
    for (int i = 0; i < 64; i += 2) {
        float ekA = kb[(size_t)i * TV];              // coalesced across v
        float ekB = kb[(size_t)(i + 1) * TV];
        float rA = fast_rcp(fmaf(eqh[i], ekA, 1.f));
        float rB = fast_rcp(fmaf(eqh[i + 1], ekB, 1.f));
        sA = fmaf(sch[i], rA, sA);
        sB = fmaf(sch[i + 1], rB, sB);
    }
    float s = sA + sB;
    if (h == 1) pb[v] = s;
    __syncthreads();

    float mk;
    {
        int idx = b * TV + v;
        bool ok;
        if (flagF)      ok = (m[4 * idx + 3] != 0);
        else if (flagB) ok = (m[idx] != 0);
        else            ok = (m[4 * idx] != 0);      // int32 LSB
        mk = ok ? __builtin_inff() : NEGV;
    }
    if (h == 0) s += pb[v];
    s = fminf(s, mk);                                // h=1 lanes: unused garbage

    int wid = tid >> 6, lane = tid & 63;
    float mm = s;
    #pragma unroll
    for (int off = 32; off >= 1; off >>= 1) mm = fmaxf(mm, __shfl_xor(mm, off));
    if (h == 0 && lane == 0) redM[wid] = mm;
    __syncthreads();
    float mfull = fmaxf(fmaxf(redM[0], redM[1]), fmaxf(redM[2], redM[3]));
    float e = __expf(s - mfull);
    float t = e;
    #pragma unroll
    for (int off = 32; off >= 1; off >>= 1) t += __shfl_xor(t, off);
    if (h == 0 && lane == 0) redS[wid] = t;
    __syncthreads();
    if (h == 0) {
        float rs = fast_rcp((redS[0] + redS[1]) + (redS[2] + redS[3]));
        weights[(size_t)blk * TV + v] = e * rs;
    }
}

// ---------------- kernel 3: context = weights @ value ----------------
// 512 blocks = b(4) x qtile(32, 8 rows) x dtile(4, 128 cols).
// 512 thr = 64 d-float2 x 8 q. Weights in LDS (broadcast); value via L1.
__global__ __launch_bounds__(512, 4) void context_kernel(
    const float* __restrict__ weights, const float* __restrict__ value,
    float* __restrict__ ctx) {
    int bid = blockIdx.x;
    int dt = bid & 3;
    int qt = (bid >> 2) & 31;
    int b = bid >> 7;
    int tid = threadIdx.x;
    int dp = tid & 63;                 // float2 column within d-tile
    int qg = tid >> 6;                 // q row within tile

    __shared__ float ws[8 * TV];       // 8 KB: 8 q-rows of weights
    ((float4*)ws)[tid] = ((const float4*)(weights + (size_t)(b * TQ + qt * 8) * TV))[tid];
    __syncthreads();

    const float2* vb = (const float2*)(value + (size_t)b * TV * DD + dt * 128) + dp;
    const float* wrow = ws + qg * TV;
    float ax = 0.f, ay = 0.f, bx = 0.f, by = 0.f;   // 2 v-phases x (d, d+1)
    #pragma unroll 8
    for (int t = 0; t < TV; t += 2) {
        float2 v0 = vb[(size_t)t * (DD / 2)];        // 512B/wave, L1-reused x8
        float2 v1 = vb[(size_t)(t + 1) * (DD / 2)];
        float w0 = wrow[t];                          // LDS broadcast
        float w1 = wrow[t + 1];
        ax = fmaf(w0, v0.x, ax); ay = fmaf(w0, v0.y, ay);
        bx = fmaf(w1, v1.x, bx); by = fmaf(w1, v1.y, by);
    }
    float2 r = make_float2(ax + bx, ay + by);
    ((float2*)(ctx + (size_t)(b * TQ + qt * 8 + qg) * DD + dt * 128))[dp] = r;
}

extern "C" void kernel_launch(void* const* d_in, const int* in_sizes, int n_in,
                              void* d_out, int out_size, void* d_ws, size_t ws_size,
                              hipStream_t stream) {
    const float* query = (const float*)d_in[0];
    const float* value = (const float*)d_in[1];
    const unsigned char* mask = (const unsigned char*)d_in[2];
    const float* W1 = (const float*)d_in[3];
    const float* W2 = (const float*)d_in[4];
    const float* scale = (const float*)d_in[5];

    float* ctx = (float*)d_out;                              // [B,TQ,D]
    float* weights = (float*)d_out + (size_t)BB * TQ * DD;   // [B,TQ,TV]

    float* eqp = (float*)d_ws;                               // 512 KB
    float* ekT = eqp + (size_t)BB * TQ * UU;                 // 512 KB

    proj_kernel<<<512, 512, 0, stream>>>(query, value, W1, W2, eqp, ekT);
    scores_kernel<<<1024, 512, 0, stream>>>(eqp, ekT, scale, mask, weights);
    context_kernel<<<512, 512, 0, stream>>>(weights, value, ctx);
}

// Round 7
// 33.215 us; speedup vs baseline: 1.6067x; 1.6067x over previous
//
#include <hip/hip_runtime.h>
#include <math.h>

#define BB 4
#define TQ 256
#define TV 256
#define DD 512
#define UU 128
#define NEGV (-1e9f)

__device__ __forceinline__ float fast_rcp(float x) {
    return __builtin_amdgcn_rcpf(x);   // v_rcp_f32
}

// ---------------- kernel 1: projections -> Eq=exp(2q) (paired), Ek=exp(2k) (transposed) ----------------
// 512 blocks x 512 thr. blocks 0..255: q-proj, 256..511: k-proj. 4 rows/block.
// threads = 128 u-cols x 4 K-quarters, combined via LDS. 4 waves/SIMD.
__global__ __launch_bounds__(512, 4) void proj_kernel(
    const float* __restrict__ query, const float* __restrict__ value,
    const float* __restrict__ W1, const float* __restrict__ W2,
    float* __restrict__ eqp /* [B*TQ/2][U][2] pairs of exp(2q) */,
    float* __restrict__ ekT /* [B][U][TV] = exp(2k) */) {
    int bid = blockIdx.x;
    int which = bid >> 8;              // 0 = q, 1 = k
    int row0 = (bid & 255) * 4;
    const float* X = which ? value : query;
    const float* W = which ? W2 : W1;

    __shared__ float xs[4 * DD];       // 8 KB: 4 input rows
    __shared__ float cmb[3][4][UU];    // 6 KB: split-K partials
    int tid = threadIdx.x;
    ((float4*)xs)[tid] = ((const float4*)(X + (size_t)row0 * DD))[tid];
    __syncthreads();

    int kc = tid >> 7;                 // K-quarter 0..3
    int u = tid & 127;
    const float* Wp = W + (size_t)(kc * (DD / 4)) * UU + u;
    const float* x0 = xs + kc * (DD / 4);
    float a0 = 0.f, a1 = 0.f, a2 = 0.f, a3 = 0.f;
    #pragma unroll 8
    for (int d = 0; d < DD / 4; ++d) {
        float w = Wp[(size_t)d * UU];          // coalesced across u
        a0 = fmaf(x0[d], w, a0);               // LDS broadcast
        a1 = fmaf(x0[DD + d], w, a1);
        a2 = fmaf(x0[2 * DD + d], w, a2);
        a3 = fmaf(x0[3 * DD + d], w, a3);
    }
    if (kc) {
        cmb[kc - 1][0][u] = a0; cmb[kc - 1][1][u] = a1;
        cmb[kc - 1][2][u] = a2; cmb[kc - 1][3][u] = a3;
    }
    __syncthreads();
    if (!kc) {
        a0 = __expf(2.f * (((a0 + cmb[0][0][u]) + cmb[1][0][u]) + cmb[2][0][u]));
        a1 = __expf(2.f * (((a1 + cmb[0][1][u]) + cmb[1][1][u]) + cmb[2][1][u]));
        a2 = __expf(2.f * (((a2 + cmb[0][2][u]) + cmb[1][2][u]) + cmb[2][2][u]));
        a3 = __expf(2.f * (((a3 + cmb[0][3][u]) + cmb[1][3][u]) + cmb[2][3][u]));
        if (which == 0) {
            int gp = row0 >> 1;                       // global row-pair index
            float2* p = (float2*)eqp;
            p[(size_t)gp * UU + u]       = make_float2(a0, a1);
            p[(size_t)(gp + 1) * UU + u] = make_float2(a2, a3);
        } else {
            int b = row0 >> 8, v0 = row0 & 255;
            float* p = ekT + ((size_t)b * UU + u) * TV + v0;
            p[0] = a0; p[1] = a1; p[2] = a2; p[3] = a3;
        }
    }
}

// ---------------- kernel 2: scores + masked softmax -> weights ----------------
// 512 blocks x 512 thr; block = 2 q-rows of one batch; thread = (v, u-half).
// s'[r,v] = -2 * sum_u sc_u * rcp(1 + Eq[r,u]*Ek[u,v])  (softmax shift-invariant:
// the +sum_u sc_u constant is common to all VALID entries; masked stay -1e9.)
__global__ __launch_bounds__(512, 4) void scores_kernel(
    const float* __restrict__ eqp, const float* __restrict__ ekT,
    const float* __restrict__ scale, const unsigned char* __restrict__ m,
    float* __restrict__ weights) {
    int blk = blockIdx.x;              // 0..511
    int b = blk >> 7;
    int gp = blk & 127;                // row pair within batch
    int tid = threadIdx.x;
    int v = tid & 255;
    int h = tid >> 8;                  // u-half

    __shared__ float2 eqL[UU];         // 1 KB
    __shared__ float sc2[UU];          // -2*scale
    __shared__ float pb[2][TV];        // 2 KB partial scores from h=1
    __shared__ int flagF, flagB;
    __shared__ float redM[2][4], redS[2][4];

    if (tid == 0) { flagF = 0; flagB = 0; }
    if (tid < UU) eqL[tid] = ((const float2*)eqp)[(size_t)(b * 128 + gp) * UU + tid];
    else if (tid < 2 * UU) sc2[tid - UU] = -2.f * scale[tid - UU];
    if (tid < 256) {                   // mask layout probe, first 1024 bytes safe
        uchar4 c4 = ((const uchar4*)m)[tid];
        if (c4.w == 0x3f) flagF = 1;                 // float32 1.0f high byte
        if (c4.y | c4.z | c4.w) flagB = 1;           // off-word nonzero -> u8
    }
    __syncthreads();

    const float* kb = ekT + ((size_t)b * UU + h * 64) * TV + v;
    float s0 = 0.f, s1 = 0.f;
    #pragma unroll                      // full unroll: deep load clustering
    for (int i = 0; i < 64; ++i) {
        float ek = kb[(size_t)i * TV];               // coalesced across v
        float2 eq2 = eqL[h * 64 + i];                // LDS broadcast
        float w2 = sc2[h * 64 + i];
        float r0 = fast_rcp(fmaf(eq2.x, ek, 1.f));
        float r1 = fast_rcp(fmaf(eq2.y, ek, 1.f));
        s0 = fmaf(w2, r0, s0);
        s1 = fmaf(w2, r1, s1);
    }
    if (h == 1) { pb[0][v] = s0; pb[1][v] = s1; }
    __syncthreads();

    float mk;
    {
        int idx = b * TV + v;
        bool ok;
        if (flagF)      ok = (m[4 * idx + 3] != 0);
        else if (flagB) ok = (m[idx] != 0);
        else            ok = (m[4 * idx] != 0);      // int32 LSB
        mk = ok ? __builtin_inff() : NEGV;
    }
    float s[2];
    s[0] = fminf(s0 + pb[0][v], mk);                 // h=1 lanes: garbage, unused
    s[1] = fminf(s1 + pb[1][v], mk);

    int wid = tid >> 6, lane = tid & 63;
    float e[2];
    #pragma unroll
    for (int r = 0; r < 2; ++r) {
        float mm = s[r];
        #pragma unroll
        for (int off = 32; off >= 1; off >>= 1) mm = fmaxf(mm, __shfl_xor(mm, off));
        if (h == 0 && lane == 0) redM[r][wid] = mm;
    }
    __syncthreads();
    #pragma unroll
    for (int r = 0; r < 2; ++r) {
        float mfull = fmaxf(fmaxf(redM[r][0], redM[r][1]),
                            fmaxf(redM[r][2], redM[r][3]));
        e[r] = __expf(s[r] - mfull);
        float t = e[r];
        #pragma unroll
        for (int off = 32; off >= 1; off >>= 1) t += __shfl_xor(t, off);
        if (h == 0 && lane == 0) redS[r][wid] = t;
    }
    __syncthreads();
    if (h == 0) {
        #pragma unroll
        for (int r = 0; r < 2; ++r) {
            float rs = fast_rcp((redS[r][0] + redS[r][1]) + (redS[r][2] + redS[r][3]));
            weights[(size_t)(b * TQ + gp * 2 + r) * TV + v] = e[r] * rs;
        }
    }
}

// ---------------- kernel 3: context partials, v-split-2 ----------------
// 512 blocks x 512 thr: (b, 4 q-rows, v-half). thread = one d column.
__global__ __launch_bounds__(512, 4) void context_kernel(
    const float* __restrict__ weights, const float* __restrict__ value,
    float* __restrict__ ctx, float* __restrict__ part) {
    int bid = blockIdx.x;
    int vh = bid & 1;
    int grp = bid >> 1;
    int b = grp >> 6;
    int q0 = (grp & 63) * 4;
    int tid = threadIdx.x;             // d column
    __shared__ float w[4][128];        // 2 KB
    if (tid < 512) {
        int r = tid >> 7, j = tid & 127;
        w[r][j] = weights[(size_t)(b * TQ + q0 + r) * TV + vh * 128 + j];
    }
    __syncthreads();
    const float* vb = value + ((size_t)b * TV + vh * 128) * DD + tid;
    float a0 = 0.f, a1 = 0.f, a2 = 0.f, a3 = 0.f;
    #pragma unroll 8
    for (int t = 0; t < 128; ++t) {
        float vv = vb[(size_t)t * DD];               // coalesced across tid
        a0 = fmaf(w[0][t], vv, a0);
        a1 = fmaf(w[1][t], vv, a1);
        a2 = fmaf(w[2][t], vv, a2);
        a3 = fmaf(w[3][t], vv, a3);
    }
    float* out = (vh ? part : ctx) + (size_t)(b * TQ + q0) * DD + tid;
    out[0 * DD] = a0; out[1 * DD] = a1; out[2 * DD] = a2; out[3 * DD] = a3;
}

// ---------------- kernel 3-fallback: full-v context (if ws too small) ----------------
__global__ __launch_bounds__(256) void context_kernel_ns(
    const float* __restrict__ weights, const float* __restrict__ value,
    float* __restrict__ ctx) {
    int bid = blockIdx.x;              // 0..511
    int half = bid & 1;
    int grp = bid >> 1;
    int b = grp >> 6;
    int q0 = (grp & 63) * 4;
    int tid = threadIdx.x;
    __shared__ float w[4 * TV];
    {
        const float* wsrc = weights + (size_t)(b * TQ + q0) * TV;
        for (int i = tid; i < 4 * TV; i += 256) w[i] = wsrc[i];
    }
    __syncthreads();
    const float* vb = value + (size_t)b * TV * DD + half * 256 + tid;
    float a0 = 0.f, a1 = 0.f, a2 = 0.f, a3 = 0.f;
    #pragma unroll 8
    for (int t = 0; t < TV; ++t) {
        float vv = vb[(size_t)t * DD];
        a0 = fmaf(w[0 * TV + t], vv, a0);
        a1 = fmaf(w[1 * TV + t], vv, a1);
        a2 = fmaf(w[2 * TV + t], vv, a2);
        a3 = fmaf(w[3 * TV + t], vv, a3);
    }
    float* out = ctx + (size_t)(b * TQ + q0) * DD + half * 256 + tid;
    out[0 * DD] = a0; out[1 * DD] = a1; out[2 * DD] = a2; out[3 * DD] = a3;
}

// ---------------- kernel 4: ctx += part (float4) ----------------
__global__ __launch_bounds__(256) void ctx_reduce_kernel(
    float* __restrict__ ctx, const float* __restrict__ part) {
    size_t i = (size_t)blockIdx.x * 256 + threadIdx.x;   // 131072 float4
    float4 a = ((const float4*)ctx)[i];
    float4 b = ((const float4*)part)[i];
    a.x += b.x; a.y += b.y; a.z += b.z; a.w += b.w;
    ((float4*)ctx)[i] = a;
}

extern "C" void kernel_launch(void* const* d_in, const int* in_sizes, int n_in,
                              void* d_out, int out_size, void* d_ws, size_t ws_size,
                              hipStream_t stream) {
    const float* query = (const float*)d_in[0];
    const float* value = (const float*)d_in[1];
    const unsigned char* mask = (const unsigned char*)d_in[2];
    const float* W1 = (const float*)d_in[3];
    const float* W2 = (const float*)d_in[4];
    const float* scale = (const float*)d_in[5];

    float* ctx = (float*)d_out;                              // [B,TQ,D]
    float* weights = (float*)d_out + (size_t)BB * TQ * DD;   // [B,TQ,TV]

    float* eqp = (float*)d_ws;                               // 512 KB (pairs)
    float* ekT = eqp + (size_t)BB * TQ * UU;                 // 512 KB
    float* part = ekT + (size_t)BB * UU * TV;                // 2 MB (ctx partials)
    size_t need = ((size_t)BB * TQ * UU * 2 + (size_t)BB * TQ * DD) * sizeof(float);

    proj_kernel<<<512, 512, 0, stream>>>(query, value, W1, W2, eqp, ekT);
    scores_kernel<<<512, 512, 0, stream>>>(eqp, ekT, scale, mask, weights);
    if (ws_size >= need) {
        context_kernel<<<512, 512, 0, stream>>>(weights, value, ctx, part);
        ctx_reduce_kernel<<<512, 256, 0, stream>>>(ctx, part);
    } else {
        context_kernel_ns<<<512, 256, 0, stream>>>(weights, value, ctx);
    }
}